// Round 3
// baseline (911.591 us; speedup 1.0000x reference)
//
#include <hip/hip_runtime.h>

#define N_NODES 100000
#define M_EDGES 1600000
#define CH 64
#define NPB 256                              // nodes per bucket (col >> 8)
#define NB ((N_NODES + NPB - 1) / NPB)       // 391 buckets
#define PART_CHUNK 8192
#define PART_BLOCKS ((M_EDGES + PART_CHUNK - 1) / PART_CHUNK)  // 196

// ---------- per-node degree histogram (excl. self-loop) ----------
__global__ __launch_bounds__(256) void k_hist(const int* __restrict__ col, int* __restrict__ cnt) {
    int e = blockIdx.x * blockDim.x + threadIdx.x;
    if (e < M_EDGES) atomicAdd(&cnt[col[e]], 1);
}

// ---------- dis = 1/sqrt(deg), deg = cnt + 1 (self-loop) ----------
__global__ __launch_bounds__(256) void k_dis(const int* __restrict__ cnt, float* __restrict__ dis) {
    int i = blockIdx.x * blockDim.x + threadIdx.x;
    if (i < N_NODES) dis[i] = 1.0f / sqrtf((float)(cnt[i] + 1));
}

// ---------- per-bucket edge counts ----------
__global__ __launch_bounds__(256) void k_bucket_cnt(const int* __restrict__ cnt, int* __restrict__ bcnt) {
    __shared__ int s;
    if (threadIdx.x == 0) s = 0;
    __syncthreads();
    int node = blockIdx.x * NPB + threadIdx.x;
    int v = (node < N_NODES) ? cnt[node] : 0;
    atomicAdd(&s, v);
    __syncthreads();
    if (threadIdx.x == 0) bcnt[blockIdx.x] = s;
}

// ---------- exclusive scan over 391 bucket counts (single block) ----------
__global__ __launch_bounds__(512) void k_bucket_scan(const int* __restrict__ bcnt, int* __restrict__ bbase,
                                                     int* __restrict__ bcur) {
    __shared__ int s[512];
    int v = (threadIdx.x < NB) ? bcnt[threadIdx.x] : 0;
    s[threadIdx.x] = v;
    __syncthreads();
    for (int off = 1; off < 512; off <<= 1) {
        int t = (threadIdx.x >= off) ? s[threadIdx.x - off] : 0;
        __syncthreads();
        s[threadIdx.x] += t;
        __syncthreads();
    }
    if (threadIdx.x < NB) {
        int e = s[threadIdx.x] - v;  // exclusive
        bbase[threadIdx.x] = e;
        bcur[threadIdx.x] = e;
    }
}

// ---------- coarse partition: pack (row<<8)|(col&255) into bucket segments ----------
__global__ __launch_bounds__(256) void k_partition(const int* __restrict__ row, const int* __restrict__ col,
                                                   int* __restrict__ bcur, unsigned int* __restrict__ pairs) {
    __shared__ int h[NB];
    int tid = threadIdx.x;
    int start = blockIdx.x * PART_CHUNK;
    int end = min(M_EDGES, start + PART_CHUNK);
    for (int i = tid; i < NB; i += 256) h[i] = 0;
    __syncthreads();
    for (int e = start + tid; e < end; e += 256)
        atomicAdd(&h[col[e] >> 8], 1);
    __syncthreads();
    for (int i = tid; i < NB; i += 256) {
        int c = h[i];
        h[i] = c ? atomicAdd(&bcur[i], c) : 0;  // block's base within bucket region
    }
    __syncthreads();
    for (int e = start + tid; e < end; e += 256) {
        int c = col[e];
        int pos = atomicAdd(&h[c >> 8], 1);
        pairs[pos] = ((unsigned int)row[e] << 8) | (unsigned int)(c & 255);
    }
}

// ---------- g = dis[r] * (x @ W) ----------
__global__ __launch_bounds__(256) void k_gemm_g(const float* __restrict__ x, const float* __restrict__ W,
                                                const float* __restrict__ dis, float* __restrict__ g) {
    __shared__ float sW[64][64];
    __shared__ float sX[64][65];
    int tid = threadIdx.x;
    int row0 = blockIdx.x * 64;

    for (int i = tid; i < 64 * 64; i += 256) sW[i >> 6][i & 63] = W[i];
    for (int i = tid; i < 64 * 64; i += 256) {
        int r = i >> 6, c = i & 63;
        int gr = row0 + r;
        sX[r][c] = (gr < N_NODES) ? x[gr * 64 + c] : 0.0f;
    }
    __syncthreads();

    int r = tid >> 2;
    int c0 = (tid & 3) * 16;
    float acc[16];
#pragma unroll
    for (int j = 0; j < 16; j++) acc[j] = 0.0f;
    for (int k = 0; k < 64; k++) {
        float xv = sX[r][k];
#pragma unroll
        for (int j = 0; j < 16; j++) acc[j] += xv * sW[k][c0 + j];
    }
    int gr = row0 + r;
    if (gr < N_NODES) {
        float d = dis[gr];
        float4* dst = reinterpret_cast<float4*>(&g[gr * 64 + c0]);
#pragma unroll
        for (int j4 = 0; j4 < 4; j4++)
            dst[j4] = make_float4(d * acc[j4 * 4 + 0], d * acc[j4 * 4 + 1],
                                  d * acc[j4 * 4 + 2], d * acc[j4 * 4 + 3]);
    }
}

// ---------- bucket aggregation: LDS accum, wave per edge, lane = channel ----------
__global__ __launch_bounds__(512) void k_bucket_agg(const int* __restrict__ bbase, const int* __restrict__ bend,
                                                    const unsigned int* __restrict__ pairs,
                                                    const float* __restrict__ dis, const float* __restrict__ g,
                                                    const float* __restrict__ bias, float* __restrict__ out) {
    __shared__ float acc[NPB * CH];  // 64 KB; lane i -> bank i%32, 2-way (free)
    int tid = threadIdx.x;
    for (int i = tid; i < NPB * CH; i += 512) acc[i] = 0.0f;
    __syncthreads();

    int b = blockIdx.x;
    int s0 = bbase[b], e0 = bend[b];  // bend = cursor after partition = base + cnt
    int wid = tid >> 6, lane = tid & 63;
    int i = s0 + wid;
    for (; i + 24 < e0; i += 32) {  // 8 waves stride 8, unroll 4 -> 4 gathers in flight
        unsigned int p0 = pairs[i], p1 = pairs[i + 8], p2 = pairs[i + 16], p3 = pairs[i + 24];
        float v0 = g[(p0 >> 8) * CH + lane];
        float v1 = g[(p1 >> 8) * CH + lane];
        float v2 = g[(p2 >> 8) * CH + lane];
        float v3 = g[(p3 >> 8) * CH + lane];
        atomicAdd(&acc[(p0 & 255u) * CH + lane], v0);
        atomicAdd(&acc[(p1 & 255u) * CH + lane], v1);
        atomicAdd(&acc[(p2 & 255u) * CH + lane], v2);
        atomicAdd(&acc[(p3 & 255u) * CH + lane], v3);
    }
    for (; i < e0; i += 8) {
        unsigned int p = pairs[i];
        float v = g[(p >> 8) * CH + lane];
        atomicAdd(&acc[(p & 255u) * CH + lane], v);
    }
    __syncthreads();

    int node0 = b * NPB;
    int nn = min(NPB, N_NODES - node0);
    for (int idx = tid; idx < nn * CH; idx += 512) {
        int loc = idx >> 6, ch = idx & 63;
        int node = node0 + loc;
        out[(size_t)node * CH + ch] = dis[node] * (acc[idx] + g[(size_t)node * CH + ch]) + bias[ch];
    }
}

extern "C" void kernel_launch(void* const* d_in, const int* in_sizes, int n_in,
                              void* d_out, int out_size, void* d_ws, size_t ws_size,
                              hipStream_t stream) {
    const float* x  = (const float*)d_in[0];
    const int*   ei = (const int*)d_in[1];  // [2, M] flat int32
    const float* W  = (const float*)d_in[2];
    const float* bv = (const float*)d_in[3];
    float* out = (float*)d_out;

    const int* row = ei;
    const int* col = ei + M_EDGES;

    // workspace layout (total ~34.4 MB):
    char* ws = (char*)d_ws;
    float*        dis   = (float*)(ws + 0);                 // 400,000 B
    int*          bbase = (int*)(ws + (512 << 10));         // 1,564 B
    int*          bcur  = (int*)(ws + (520 << 10));         // 1,564 B
    int*          bcnt  = (int*)(ws + (528 << 10));         // 1,564 B
    float*        g     = (float*)(ws + (1 << 20));         // 25,600,000 B (1 MB .. 26.6 MB)
    unsigned int* pairs = (unsigned int*)(ws + (28u << 20)); // 6,400,000 B (28 .. 34.4 MB)
    int*          cnt   = (int*)(ws + (28u << 20));         // 400 KB, overlaps pairs (dead before partition)

    hipMemsetAsync(cnt, 0, N_NODES * sizeof(int), stream);

    k_hist<<<(M_EDGES + 255) / 256, 256, 0, stream>>>(col, cnt);
    k_dis<<<(N_NODES + 255) / 256, 256, 0, stream>>>(cnt, dis);
    k_bucket_cnt<<<NB, 256, 0, stream>>>(cnt, bcnt);
    k_bucket_scan<<<1, 512, 0, stream>>>(bcnt, bbase, bcur);

    k_gemm_g<<<(N_NODES + 63) / 64, 256, 0, stream>>>(x, W, dis, g);

    k_partition<<<PART_BLOCKS, 256, 0, stream>>>(row, col, bcur, pairs);

    // after partition, bcur[b] == bbase[b] + bucket count == end offset
    k_bucket_agg<<<NB, 512, 0, stream>>>(bbase, bcur, pairs, dis, g, bv, out);
}

// Round 4
// 306.362 us; speedup vs baseline: 2.9755x; 2.9755x over previous
//
#include <hip/hip_runtime.h>

#define N_NODES 100000
#define M_EDGES 1600000
#define CH 64
#define NPB 256                              // nodes per bucket (col >> 8)
#define NB ((N_NODES + NPB - 1) / NPB)       // 391 buckets
#define PART_CHUNK 8192
#define PART_BLOCKS ((M_EDGES + PART_CHUNK - 1) / PART_CHUNK)  // 196
#define REG_E 24                             // max edges/thread in fine sort (bucket cap 6144 = 32 sigma)

// ---------- per-node degree histogram (excl. self-loop) ----------
__global__ __launch_bounds__(256) void k_hist(const int* __restrict__ col, int* __restrict__ cnt) {
    int e = blockIdx.x * blockDim.x + threadIdx.x;
    if (e < M_EDGES) atomicAdd(&cnt[col[e]], 1);
}

// ---------- dis = 1/sqrt(deg), deg = cnt + 1 (self-loop) ----------
__global__ __launch_bounds__(256) void k_dis(const int* __restrict__ cnt, float* __restrict__ dis) {
    int i = blockIdx.x * blockDim.x + threadIdx.x;
    if (i < N_NODES) dis[i] = 1.0f / sqrtf((float)(cnt[i] + 1));
}

// ---------- per-bucket edge counts ----------
__global__ __launch_bounds__(256) void k_bucket_cnt(const int* __restrict__ cnt, int* __restrict__ bcnt) {
    __shared__ int s;
    if (threadIdx.x == 0) s = 0;
    __syncthreads();
    int node = blockIdx.x * NPB + threadIdx.x;
    int v = (node < N_NODES) ? cnt[node] : 0;
    atomicAdd(&s, v);
    __syncthreads();
    if (threadIdx.x == 0) bcnt[blockIdx.x] = s;
}

// ---------- exclusive scan over 391 bucket counts (single block) ----------
__global__ __launch_bounds__(512) void k_bucket_scan(const int* __restrict__ bcnt, int* __restrict__ bbase,
                                                     int* __restrict__ bcur) {
    __shared__ int s[512];
    int v = (threadIdx.x < NB) ? bcnt[threadIdx.x] : 0;
    s[threadIdx.x] = v;
    __syncthreads();
    for (int off = 1; off < 512; off <<= 1) {
        int t = (threadIdx.x >= off) ? s[threadIdx.x - off] : 0;
        __syncthreads();
        s[threadIdx.x] += t;
        __syncthreads();
    }
    if (threadIdx.x < NB) {
        int e = s[threadIdx.x] - v;  // exclusive
        bbase[threadIdx.x] = e;
        bcur[threadIdx.x] = e;
    }
}

// ---------- coarse partition: pack (row<<8)|(col&255) into bucket segments ----------
__global__ __launch_bounds__(256) void k_partition(const int* __restrict__ row, const int* __restrict__ col,
                                                   int* __restrict__ bcur, unsigned int* __restrict__ pairs) {
    __shared__ int h[NB];
    int tid = threadIdx.x;
    int start = blockIdx.x * PART_CHUNK;
    int end = min(M_EDGES, start + PART_CHUNK);
    for (int i = tid; i < NB; i += 256) h[i] = 0;
    __syncthreads();
    for (int e = start + tid; e < end; e += 256)
        atomicAdd(&h[col[e] >> 8], 1);
    __syncthreads();
    for (int i = tid; i < NB; i += 256) {
        int c = h[i];
        h[i] = c ? atomicAdd(&bcur[i], c) : 0;  // block's contiguous sub-range within bucket region
    }
    __syncthreads();
    for (int e = start + tid; e < end; e += 256) {
        int c = col[e];
        int pos = atomicAdd(&h[c >> 8], 1);
        pairs[pos] = ((unsigned int)row[e] << 8) | (unsigned int)(c & 255);
    }
}

// ---------- in-place per-bucket counting sort + per-node start offsets ----------
// Reads the bucket's pairs into registers (ALL reads before ANY write -> in-place safe),
// LDS count + scan over 256 local nodes, scatter rows back into pairs[] at sorted positions.
__global__ __launch_bounds__(256) void k_fine(const int* __restrict__ bbase, const int* __restrict__ bend,
                                              unsigned int* __restrict__ pairs, int* __restrict__ node_start) {
    __shared__ int lcnt[NPB];
    __shared__ int lcur[NPB];
    __shared__ int ss[NPB];
    int b = blockIdx.x, t = threadIdx.x;
    int s0 = bbase[b], e0 = bend[b];

    lcnt[t] = 0;
    __syncthreads();

    unsigned int reg[REG_E];  // compile-time indexed only (rule #20)
#pragma unroll
    for (int k = 0; k < REG_E; k++) {
        int e = s0 + t + k * 256;
        if (e < e0) {
            unsigned int p = pairs[e];
            reg[k] = p;
            atomicAdd(&lcnt[p & 255u], 1);
        }
    }
    __syncthreads();

    int v = lcnt[t];
    ss[t] = v;
    __syncthreads();
    for (int off = 1; off < NPB; off <<= 1) {
        int tv = (t >= off) ? ss[t - off] : 0;
        __syncthreads();
        ss[t] += tv;
        __syncthreads();
    }
    int excl = ss[t] - v;
    lcur[t] = excl;
    int node = b * NPB + t;
    if (node < N_NODES) node_start[node] = s0 + excl;
    __syncthreads();

#pragma unroll
    for (int k = 0; k < REG_E; k++) {
        int e = s0 + t + k * 256;
        if (e < e0) {
            unsigned int p = reg[k];
            int pos = atomicAdd(&lcur[p & 255u], 1);
            pairs[s0 + pos] = p >> 8;  // now holds row only, grouped by target node
        }
    }
}

// ---------- g = dis[r] * (x @ W) ----------
__global__ __launch_bounds__(256) void k_gemm_g(const float* __restrict__ x, const float* __restrict__ W,
                                                const float* __restrict__ dis, float* __restrict__ g) {
    __shared__ float sW[64][64];
    __shared__ float sX[64][65];
    int tid = threadIdx.x;
    int row0 = blockIdx.x * 64;

    for (int i = tid; i < 64 * 64; i += 256) sW[i >> 6][i & 63] = W[i];
    for (int i = tid; i < 64 * 64; i += 256) {
        int r = i >> 6, c = i & 63;
        int gr = row0 + r;
        sX[r][c] = (gr < N_NODES) ? x[gr * 64 + c] : 0.0f;
    }
    __syncthreads();

    int r = tid >> 2;
    int c0 = (tid & 3) * 16;
    float acc[16];
#pragma unroll
    for (int j = 0; j < 16; j++) acc[j] = 0.0f;
    for (int k = 0; k < 64; k++) {
        float xv = sX[r][k];
#pragma unroll
        for (int j = 0; j < 16; j++) acc[j] += xv * sW[k][c0 + j];
    }
    int gr = row0 + r;
    if (gr < N_NODES) {
        float d = dis[gr];
        float4* dst = reinterpret_cast<float4*>(&g[gr * 64 + c0]);
#pragma unroll
        for (int j4 = 0; j4 < 4; j4++)
            dst[j4] = make_float4(d * acc[j4 * 4 + 0], d * acc[j4 * 4 + 1],
                                  d * acc[j4 * 4 + 2], d * acc[j4 * 4 + 3]);
    }
}

// ---------- per-node aggregation: wave per node, lane = channel, register acc ----------
// out[c] = dis[c] * (sum_e g[srow_e] + g[c]) + b
__global__ __launch_bounds__(256) void k_aggregate(const int* __restrict__ node_start, const int* __restrict__ cnt,
                                                   const int* __restrict__ srow, const float* __restrict__ dis,
                                                   const float* __restrict__ g, const float* __restrict__ bias,
                                                   float* __restrict__ out) {
    int node = blockIdx.x * 4 + (threadIdx.x >> 6);
    int lane = threadIdx.x & 63;
    if (node >= N_NODES) return;
    int s0 = node_start[node];
    int e0 = s0 + cnt[node];
    float acc = g[(size_t)node * CH + lane];  // self-loop term
    int i = s0;
    for (; i + 4 <= e0; i += 4) {
        int r0 = srow[i], r1 = srow[i + 1], r2 = srow[i + 2], r3 = srow[i + 3];
        float v0 = g[(size_t)r0 * CH + lane];
        float v1 = g[(size_t)r1 * CH + lane];
        float v2 = g[(size_t)r2 * CH + lane];
        float v3 = g[(size_t)r3 * CH + lane];
        acc += v0;
        acc += v1;
        acc += v2;
        acc += v3;
    }
    for (; i < e0; i++) acc += g[(size_t)srow[i] * CH + lane];
    out[(size_t)node * CH + lane] = dis[node] * acc + bias[lane];
}

extern "C" void kernel_launch(void* const* d_in, const int* in_sizes, int n_in,
                              void* d_out, int out_size, void* d_ws, size_t ws_size,
                              hipStream_t stream) {
    const float* x  = (const float*)d_in[0];
    const int*   ei = (const int*)d_in[1];  // [2, M] flat int32
    const float* W  = (const float*)d_in[2];
    const float* bv = (const float*)d_in[3];
    float* out = (float*)d_out;

    const int* row = ei;
    const int* col = ei + M_EDGES;

    // workspace layout (34.4 MB total — same proven footprint as rounds 2/3):
    char* ws = (char*)d_ws;
    int*          cnt   = (int*)(ws + 0);                    // 400,000 B (alive through aggregate)
    float*        dis   = (float*)(ws + (512 << 10));        // 400,000 B
    int*          nstart= (int*)(ws + (1024 << 10));         // 400,000 B
    int*          bcnt  = (int*)(ws + (1536 << 10));         // 1,564 B
    int*          bbase = (int*)(ws + (1544 << 10));         // 1,564 B
    int*          bcur  = (int*)(ws + (1552 << 10));         // 1,564 B
    float*        g     = (float*)(ws + (2u << 20));         // 25,600,000 B (2 .. 27.6 MB)
    unsigned int* pairs = (unsigned int*)(ws + (28u << 20)); // 6,400,000 B (28 .. 34.4 MB)

    hipMemsetAsync(cnt, 0, N_NODES * sizeof(int), stream);

    k_hist<<<(M_EDGES + 255) / 256, 256, 0, stream>>>(col, cnt);
    k_dis<<<(N_NODES + 255) / 256, 256, 0, stream>>>(cnt, dis);
    k_bucket_cnt<<<NB, 256, 0, stream>>>(cnt, bcnt);
    k_bucket_scan<<<1, 512, 0, stream>>>(bcnt, bbase, bcur);

    k_gemm_g<<<(N_NODES + 63) / 64, 256, 0, stream>>>(x, W, dis, g);

    k_partition<<<PART_BLOCKS, 256, 0, stream>>>(row, col, bcur, pairs);

    // after partition, bcur[b] == bbase[b] + bucket count == end offset
    k_fine<<<NB, 256, 0, stream>>>(bbase, bcur, pairs, nstart);

    // pairs now holds rows sorted by target node; ranges via nstart/cnt
    k_aggregate<<<(N_NODES + 3) / 4, 256, 0, stream>>>(nstart, cnt, (const int*)pairs, dis, g, bv, out);
}

// Round 5
// 232.250 us; speedup vs baseline: 3.9250x; 1.3191x over previous
//
#include <hip/hip_runtime.h>

#define N_NODES 100000
#define M_EDGES 1600000
#define CH 64
#define NPB 256                              // nodes per bucket (col >> 8)
#define NB ((N_NODES + NPB - 1) / NPB)       // 391 buckets
#define PART_CHUNK 8192
#define PART_BLOCKS ((M_EDGES + PART_CHUNK - 1) / PART_CHUNK)  // 196
#define REG_E 24                             // bucket cap 6144 ≈ mean 4096 + 32 sigma

// f32 -> bf16 (RNE) pack of two channels into one uint
__device__ __forceinline__ unsigned int pack_bf16x2(float a, float b) {
    unsigned int ua = __float_as_uint(a);
    ua = (ua + 0x7fffu + ((ua >> 16) & 1u)) >> 16;
    unsigned int ub = __float_as_uint(b);
    ub = (ub + 0x7fffu + ((ub >> 16) & 1u)) >> 16;
    return ua | (ub << 16);
}
__device__ __forceinline__ float bf_lo(unsigned int u) { return __uint_as_float(u << 16); }
__device__ __forceinline__ float bf_hi(unsigned int u) { return __uint_as_float(u & 0xffff0000u); }

// ---------- bucket histogram: 391-bin LDS hist per chunk ----------
__global__ __launch_bounds__(256) void k_bhist(const int* __restrict__ col, int* __restrict__ bcnt) {
    __shared__ int h[NB];
    int tid = threadIdx.x;
    for (int i = tid; i < NB; i += 256) h[i] = 0;
    __syncthreads();
    int start = blockIdx.x * PART_CHUNK;
    int end = min(M_EDGES, start + PART_CHUNK);
    for (int e = start + tid; e < end; e += 256) atomicAdd(&h[col[e] >> 8], 1);
    __syncthreads();
    for (int i = tid; i < NB; i += 256)
        if (h[i]) atomicAdd(&bcnt[i], h[i]);
}

// ---------- exclusive scan over 391 bucket counts (single block) ----------
__global__ __launch_bounds__(512) void k_bucket_scan(const int* __restrict__ bcnt, int* __restrict__ bbase,
                                                     int* __restrict__ bcur) {
    __shared__ int s[512];
    int v = (threadIdx.x < NB) ? bcnt[threadIdx.x] : 0;
    s[threadIdx.x] = v;
    __syncthreads();
    for (int off = 1; off < 512; off <<= 1) {
        int t = (threadIdx.x >= off) ? s[threadIdx.x - off] : 0;
        __syncthreads();
        s[threadIdx.x] += t;
        __syncthreads();
    }
    if (threadIdx.x < NB) {
        int e = s[threadIdx.x] - v;  // exclusive
        bbase[threadIdx.x] = e;
        bcur[threadIdx.x] = e;
    }
}

// ---------- coarse partition: pack (row<<8)|(col&255) into bucket segments ----------
__global__ __launch_bounds__(256) void k_partition(const int* __restrict__ row, const int* __restrict__ col,
                                                   int* __restrict__ bcur, unsigned int* __restrict__ pairs) {
    __shared__ int h[NB];
    int tid = threadIdx.x;
    int start = blockIdx.x * PART_CHUNK;
    int end = min(M_EDGES, start + PART_CHUNK);
    for (int i = tid; i < NB; i += 256) h[i] = 0;
    __syncthreads();
    for (int e = start + tid; e < end; e += 256)
        atomicAdd(&h[col[e] >> 8], 1);
    __syncthreads();
    for (int i = tid; i < NB; i += 256) {
        int c = h[i];
        h[i] = c ? atomicAdd(&bcur[i], c) : 0;  // block's contiguous sub-range within bucket
    }
    __syncthreads();
    for (int e = start + tid; e < end; e += 256) {
        int c = col[e];
        int pos = atomicAdd(&h[c >> 8], 1);
        pairs[pos] = ((unsigned int)row[e] << 8) | (unsigned int)(c & 255);
    }
}

// ---------- in-place per-bucket counting sort; emits nstart (+sentinel) and dis ----------
__global__ __launch_bounds__(256) void k_fine(const int* __restrict__ bbase, const int* __restrict__ bend,
                                              unsigned int* __restrict__ pairs, int* __restrict__ node_start,
                                              float* __restrict__ dis) {
    __shared__ int lcnt[NPB];
    __shared__ int lcur[NPB];
    __shared__ int ss[NPB];
    int b = blockIdx.x, t = threadIdx.x;
    int s0 = bbase[b], e0 = bend[b];

    lcnt[t] = 0;
    __syncthreads();

    unsigned int reg[REG_E];  // compile-time indexed only (rule #20)
#pragma unroll
    for (int k = 0; k < REG_E; k++) {
        int e = s0 + t + k * 256;
        if (e < e0) {
            unsigned int p = pairs[e];
            reg[k] = p;
            atomicAdd(&lcnt[p & 255u], 1);
        }
    }
    __syncthreads();

    int v = lcnt[t];
    ss[t] = v;
    __syncthreads();
    for (int off = 1; off < NPB; off <<= 1) {
        int tv = (t >= off) ? ss[t - off] : 0;
        __syncthreads();
        ss[t] += tv;
        __syncthreads();
    }
    int excl = ss[t] - v;
    lcur[t] = excl;
    int node = b * NPB + t;
    if (node < N_NODES) {
        node_start[node] = s0 + excl;
        dis[node] = 1.0f / sqrtf((float)(v + 1));  // degree incl. self-loop
    }
    if (b == NB - 1 && t == 0) node_start[N_NODES] = e0;  // sentinel
    __syncthreads();

#pragma unroll
    for (int k = 0; k < REG_E; k++) {
        int e = s0 + t + k * 256;
        if (e < e0) {
            unsigned int p = reg[k];
            int pos = atomicAdd(&lcur[p & 255u], 1);
            pairs[s0 + pos] = p >> 8;  // rows grouped by target node
        }
    }
}

// ---------- g = dis[r] * (x @ W), stored as packed bf16 ----------
__global__ __launch_bounds__(256) void k_gemm_g(const float* __restrict__ x, const float* __restrict__ W,
                                                const float* __restrict__ dis, unsigned int* __restrict__ g2) {
    __shared__ float sW[64][64];
    __shared__ float sX[64][65];
    int tid = threadIdx.x;
    int row0 = blockIdx.x * 64;

    for (int i = tid; i < 64 * 64; i += 256) sW[i >> 6][i & 63] = W[i];
    for (int i = tid; i < 64 * 64; i += 256) {
        int r = i >> 6, c = i & 63;
        int gr = row0 + r;
        sX[r][c] = (gr < N_NODES) ? x[gr * 64 + c] : 0.0f;
    }
    __syncthreads();

    int r = tid >> 2;
    int c0 = (tid & 3) * 16;
    float acc[16];
#pragma unroll
    for (int j = 0; j < 16; j++) acc[j] = 0.0f;
    for (int k = 0; k < 64; k++) {
        float xv = sX[r][k];
#pragma unroll
        for (int j = 0; j < 16; j++) acc[j] += xv * sW[k][c0 + j];
    }
    int gr = row0 + r;
    if (gr < N_NODES) {
        float d = dis[gr];
        unsigned int base = gr * 32 + (tid & 3) * 8;
        uint4 w0, w1;
        w0.x = pack_bf16x2(d * acc[0], d * acc[1]);
        w0.y = pack_bf16x2(d * acc[2], d * acc[3]);
        w0.z = pack_bf16x2(d * acc[4], d * acc[5]);
        w0.w = pack_bf16x2(d * acc[6], d * acc[7]);
        w1.x = pack_bf16x2(d * acc[8], d * acc[9]);
        w1.y = pack_bf16x2(d * acc[10], d * acc[11]);
        w1.z = pack_bf16x2(d * acc[12], d * acc[13]);
        w1.w = pack_bf16x2(d * acc[14], d * acc[15]);
        *reinterpret_cast<uint4*>(&g2[base]) = w0;
        *reinterpret_cast<uint4*>(&g2[base + 4]) = w1;
    }
}

// ---------- aggregation: wave per node, 2 edges/iteration (lane halves), bf16 gathers ----------
// out[c] = dis[c] * (sum_e g[srow_e] + g[c]) + b
__global__ __launch_bounds__(256) void k_aggregate(const int* __restrict__ nstart, const int* __restrict__ srow,
                                                   const float* __restrict__ dis, const unsigned int* __restrict__ g2,
                                                   const float* __restrict__ bias, float* __restrict__ out) {
    int node = blockIdx.x * 4 + (threadIdx.x >> 6);
    int l = threadIdx.x & 63;
    if (node >= N_NODES) return;
    int p = l & 31;      // channel pair index: channels (2p, 2p+1)
    int half = l >> 5;   // which edge of the pair this lane handles
    int s0 = nstart[node];
    int e0 = nstart[node + 1];
    float ax = 0.0f, ay = 0.0f;
    int i = s0;
    for (; i + 8 <= e0; i += 8) {  // 8 edges via 4 packed loads in flight
        int r0 = srow[i + half];
        int r1 = srow[i + 2 + half];
        int r2 = srow[i + 4 + half];
        int r3 = srow[i + 6 + half];
        unsigned int u0 = g2[(unsigned int)r0 * 32 + p];
        unsigned int u1 = g2[(unsigned int)r1 * 32 + p];
        unsigned int u2 = g2[(unsigned int)r2 * 32 + p];
        unsigned int u3 = g2[(unsigned int)r3 * 32 + p];
        ax += bf_lo(u0); ay += bf_hi(u0);
        ax += bf_lo(u1); ay += bf_hi(u1);
        ax += bf_lo(u2); ay += bf_hi(u2);
        ax += bf_lo(u3); ay += bf_hi(u3);
    }
    for (; i < e0; i += 2) {  // remainder, 2 edges (or 1) at a time
        int e = i + half;
        int r = srow[min(e, e0 - 1)];
        unsigned int u = g2[(unsigned int)r * 32 + p];
        if (e < e0) { ax += bf_lo(u); ay += bf_hi(u); }
    }
    // merge the two edge-halves
    ax += __shfl_xor(ax, 32, 64);
    ay += __shfl_xor(ay, 32, 64);
    // self-loop term (added once, post-merge)
    unsigned int su = g2[(unsigned int)node * 32 + p];
    ax += bf_lo(su); ay += bf_hi(su);
    float d = dis[node];
    int ch = 2 * p + half;                 // lane-permuted but fully coalesced 256B store
    float v = half ? ay : ax;
    out[(size_t)node * CH + ch] = d * v + bias[ch];
}

extern "C" void kernel_launch(void* const* d_in, const int* in_sizes, int n_in,
                              void* d_out, int out_size, void* d_ws, size_t ws_size,
                              hipStream_t stream) {
    const float* x  = (const float*)d_in[0];
    const int*   ei = (const int*)d_in[1];  // [2, M] flat int32
    const float* W  = (const float*)d_in[2];
    const float* bv = (const float*)d_in[3];
    float* out = (float*)d_out;

    const int* row = ei;
    const int* col = ei + M_EDGES;

    // workspace layout (~22.5 MB):
    char* ws = (char*)d_ws;
    int*          bcnt  = (int*)(ws + 0);                    // 1,564 B
    int*          bbase = (int*)(ws + (8 << 10));            // 1,564 B
    int*          bcur  = (int*)(ws + (16 << 10));           // 1,564 B
    float*        dis   = (float*)(ws + (512 << 10));        // 400,000 B
    int*          nstart= (int*)(ws + (1024 << 10));         // 400,004 B (N+1, sentinel)
    unsigned int* g2    = (unsigned int*)(ws + (2u << 20));  // 12,800,000 B bf16 g (2 .. 14.3 MB)
    unsigned int* pairs = (unsigned int*)(ws + (16u << 20)); // 6,400,000 B (16 .. 22.4 MB)

    hipMemsetAsync(bcnt, 0, NB * sizeof(int), stream);

    k_bhist<<<PART_BLOCKS, 256, 0, stream>>>(col, bcnt);
    k_bucket_scan<<<1, 512, 0, stream>>>(bcnt, bbase, bcur);
    k_partition<<<PART_BLOCKS, 256, 0, stream>>>(row, col, bcur, pairs);

    // after partition, bcur[b] == bbase[b] + bucket count == end offset
    k_fine<<<NB, 256, 0, stream>>>(bbase, bcur, pairs, nstart, dis);

    k_gemm_g<<<(N_NODES + 63) / 64, 256, 0, stream>>>(x, W, dis, g2);

    // pairs now holds rows sorted by target node; ranges via nstart[n] .. nstart[n+1]
    k_aggregate<<<(N_NODES + 3) / 4, 256, 0, stream>>>(nstart, (const int*)pairs, dis, g2, bv, out);
}

// Round 6
// 209.573 us; speedup vs baseline: 4.3498x; 1.1082x over previous
//
#include <hip/hip_runtime.h>

#define N_NODES 100000
#define M_EDGES 1600000
#define CH 64
#define NPB 256                              // nodes per bucket (col >> 8)
#define NB ((N_NODES + NPB - 1) / NPB)       // 391 buckets
#define PART_CHUNK 8192
#define PART_BLOCKS ((M_EDGES + PART_CHUNK - 1) / PART_CHUNK)  // 196
#define REG_E 12                             // 512 thr * 12 = 6144 bucket cap (mean 4092, +32 sigma)
#define GROWS 192                            // gemm rows per block
#define GBLKS ((N_NODES + GROWS - 1) / GROWS)  // 521

// f32 -> bf16 (RNE) pack of two channels into one uint
__device__ __forceinline__ unsigned int pack_bf16x2(float a, float b) {
    unsigned int ua = __float_as_uint(a);
    ua = (ua + 0x7fffu + ((ua >> 16) & 1u)) >> 16;
    unsigned int ub = __float_as_uint(b);
    ub = (ub + 0x7fffu + ((ub >> 16) & 1u)) >> 16;
    return ua | (ub << 16);
}
__device__ __forceinline__ float bf_lo(unsigned int u) { return __uint_as_float(u << 16); }
__device__ __forceinline__ float bf_hi(unsigned int u) { return __uint_as_float(u & 0xffff0000u); }

// ---------- bucket histogram: per-chunk 391-bin hist -> table T[chunk][bucket] ----------
__global__ __launch_bounds__(256) void k_bhist(const int* __restrict__ col, int* __restrict__ T) {
    __shared__ int h[NB];
    int tid = threadIdx.x;
    for (int i = tid; i < NB; i += 256) h[i] = 0;
    __syncthreads();
    int start = blockIdx.x * PART_CHUNK;
    int end = min(M_EDGES, start + PART_CHUNK);
    for (int e = start + tid; e < end; e += 256) atomicAdd(&h[col[e] >> 8], 1);
    __syncthreads();
    for (int i = tid; i < NB; i += 256) T[blockIdx.x * NB + i] = h[i];
}

// ---------- per-bucket: exclusive scan of T column (over chunks) in-place; emit tot ----------
__global__ __launch_bounds__(256) void k_colsum(int* __restrict__ T, int* __restrict__ tot) {
    __shared__ int s[256];
    int b = blockIdx.x, t = threadIdx.x;
    int v = (t < PART_BLOCKS) ? T[t * NB + b] : 0;
    s[t] = v;
    __syncthreads();
    for (int off = 1; off < 256; off <<= 1) {
        int tv = (t >= off) ? s[t - off] : 0;
        __syncthreads();
        s[t] += tv;
        __syncthreads();
    }
    if (t < PART_BLOCKS) T[t * NB + b] = s[t] - v;  // exclusive prefix over chunks
    if (t == 255) tot[b] = s[255];
}

// ---------- exclusive scan over 391 bucket totals -> bbase (+ sentinel) ----------
__global__ __launch_bounds__(512) void k_bucket_scan(const int* __restrict__ tot, int* __restrict__ bbase) {
    __shared__ int s[512];
    int v = (threadIdx.x < NB) ? tot[threadIdx.x] : 0;
    s[threadIdx.x] = v;
    __syncthreads();
    for (int off = 1; off < 512; off <<= 1) {
        int t = (threadIdx.x >= off) ? s[threadIdx.x - off] : 0;
        __syncthreads();
        s[threadIdx.x] += t;
        __syncthreads();
    }
    if (threadIdx.x < NB) bbase[threadIdx.x] = s[threadIdx.x] - v;  // exclusive
    if (threadIdx.x == NB - 1) bbase[NB] = s[NB - 1];               // sentinel = M
}

// ---------- coarse partition: single pass, bases from T, no global atomics ----------
__global__ __launch_bounds__(256) void k_partition(const int* __restrict__ row, const int* __restrict__ col,
                                                   const int* __restrict__ bbase, const int* __restrict__ T,
                                                   unsigned int* __restrict__ pairs) {
    __shared__ int h[NB];
    int tid = threadIdx.x;
    int c = blockIdx.x;
    for (int i = tid; i < NB; i += 256) h[i] = bbase[i] + T[c * NB + i];
    __syncthreads();
    int start = c * PART_CHUNK;
    int end = min(M_EDGES, start + PART_CHUNK);
    for (int e = start + tid; e < end; e += 256) {
        int cc = col[e];
        int pos = atomicAdd(&h[cc >> 8], 1);
        pairs[pos] = ((unsigned int)row[e] << 8) | (unsigned int)(cc & 255);
    }
}

// ---------- in-place per-bucket counting sort; emits nstart (+sentinel) and dis ----------
__global__ __launch_bounds__(512) void k_fine(const int* __restrict__ bbase,
                                              unsigned int* __restrict__ pairs, int* __restrict__ node_start,
                                              float* __restrict__ dis) {
    __shared__ int lcnt[NPB];
    __shared__ int lcur[NPB];
    __shared__ int ss[NPB];
    int b = blockIdx.x, t = threadIdx.x;
    int s0 = bbase[b], e0 = bbase[b + 1];

    if (t < NPB) lcnt[t] = 0;
    __syncthreads();

    unsigned int reg[REG_E];  // compile-time indexed only (rule #20)
#pragma unroll
    for (int k = 0; k < REG_E; k++) {
        int e = s0 + t + k * 512;
        if (e < e0) {
            unsigned int p = pairs[e];
            reg[k] = p;
            atomicAdd(&lcnt[p & 255u], 1);
        }
    }
    __syncthreads();

    int v = 0;
    if (t < NPB) { v = lcnt[t]; ss[t] = v; }
    __syncthreads();
    for (int off = 1; off < NPB; off <<= 1) {
        int tv = (t < NPB && t >= off) ? ss[t - off] : 0;
        __syncthreads();
        if (t < NPB) ss[t] += tv;
        __syncthreads();
    }
    if (t < NPB) {
        int excl = ss[t] - v;
        lcur[t] = excl;
        int node = b * NPB + t;
        if (node < N_NODES) {
            node_start[node] = s0 + excl;
            dis[node] = 1.0f / sqrtf((float)(v + 1));  // degree incl. self-loop
        }
        if (b == NB - 1 && t == 0) node_start[N_NODES] = e0;  // sentinel
    }
    __syncthreads();

#pragma unroll
    for (int k = 0; k < REG_E; k++) {
        int e = s0 + t + k * 512;
        if (e < e0) {
            unsigned int p = reg[k];
            int pos = atomicAdd(&lcur[p & 255u], 1);
            pairs[s0 + pos] = p >> 8;  // rows grouped by target node
        }
    }
}

// ---------- g = dis[r] * (x @ W), packed bf16; wave = 16-col quad, lane = row, 3 rows/thread ----------
__global__ __launch_bounds__(256) void k_gemm_g(const float* __restrict__ x, const float* __restrict__ W,
                                                const float* __restrict__ dis, unsigned int* __restrict__ g2) {
    __shared__ float sW[64][64];
    __shared__ float sXf[GROWS * 65];  // [row][k] with +1 pad: bank = (row + k) % 32, 2-way free
    int t = threadIdx.x;
    int row0 = blockIdx.x * GROWS;
    int nrows = min(GROWS, N_NODES - row0);

    for (int i = t; i < 64 * 64; i += 256) sW[i >> 6][i & 63] = W[i];
    const float4* xv = (const float4*)x;
    for (int idx = t; idx < GROWS * 16; idx += 256) {
        int r = idx >> 4, c4 = idx & 15;
        float4 v = (r < nrows) ? xv[(size_t)(row0 + r) * 16 + c4] : make_float4(0.f, 0.f, 0.f, 0.f);
        sXf[r * 65 + c4 * 4 + 0] = v.x;
        sXf[r * 65 + c4 * 4 + 1] = v.y;
        sXf[r * 65 + c4 * 4 + 2] = v.z;
        sXf[r * 65 + c4 * 4 + 3] = v.w;
    }
    __syncthreads();

    int q = t >> 6;          // wave id -> col quad
    int rid = t & 63;        // lane -> row
    int c0 = q * 16;
    float acc0[16], acc1[16], acc2[16];
#pragma unroll
    for (int j = 0; j < 16; j++) { acc0[j] = 0.f; acc1[j] = 0.f; acc2[j] = 0.f; }

    for (int k = 0; k < 64; k++) {
        float xv0 = sXf[rid * 65 + k];
        float xv1 = sXf[(rid + 64) * 65 + k];
        float xv2 = sXf[(rid + 128) * 65 + k];
        const float4* wp = (const float4*)&sW[k][c0];  // same addr across wave: b128 broadcast
        float4 w0 = wp[0], w1 = wp[1], w2 = wp[2], w3 = wp[3];
        float wv[16] = {w0.x, w0.y, w0.z, w0.w, w1.x, w1.y, w1.z, w1.w,
                        w2.x, w2.y, w2.z, w2.w, w3.x, w3.y, w3.z, w3.w};
#pragma unroll
        for (int j = 0; j < 16; j++) {
            acc0[j] += xv0 * wv[j];
            acc1[j] += xv1 * wv[j];
            acc2[j] += xv2 * wv[j];
        }
    }

#pragma unroll
    for (int jr = 0; jr < 3; jr++) {
        int r = rid + jr * 64;
        int gr = row0 + r;
        if (r < nrows) {
            float* accp = (jr == 0) ? acc0 : (jr == 1) ? acc1 : acc2;  // compile-time select (unrolled)
            float d = dis[gr];
            uint4 wlo, whi;
            wlo.x = pack_bf16x2(d * accp[0], d * accp[1]);
            wlo.y = pack_bf16x2(d * accp[2], d * accp[3]);
            wlo.z = pack_bf16x2(d * accp[4], d * accp[5]);
            wlo.w = pack_bf16x2(d * accp[6], d * accp[7]);
            whi.x = pack_bf16x2(d * accp[8], d * accp[9]);
            whi.y = pack_bf16x2(d * accp[10], d * accp[11]);
            whi.z = pack_bf16x2(d * accp[12], d * accp[13]);
            whi.w = pack_bf16x2(d * accp[14], d * accp[15]);
            unsigned int base = (unsigned int)gr * 32 + q * 8;
            *reinterpret_cast<uint4*>(&g2[base]) = wlo;
            *reinterpret_cast<uint4*>(&g2[base + 4]) = whi;
        }
    }
}

// ---------- aggregation: wave per node, 16 lanes/edge (uint2 = 4 ch), 16 edges/iter ----------
// out[c] = dis[c] * (sum_e g[srow_e] + g[c]) + b
__global__ __launch_bounds__(256) void k_aggregate(const int* __restrict__ nstart, const int* __restrict__ srow,
                                                   const float* __restrict__ dis, const unsigned int* __restrict__ g2,
                                                   const float* __restrict__ bias, float* __restrict__ out) {
    int node = blockIdx.x * 4 + (threadIdx.x >> 6);
    int l = threadIdx.x & 63;
    if (node >= N_NODES) return;
    int grp = l >> 4;   // edge slot within iteration
    int sub = l & 15;   // channel quad: channels 4*sub .. 4*sub+3
    const uint2* gq = (const uint2*)g2;  // one g-row = 16 uint2
    int s0 = nstart[node];
    int e0 = nstart[node + 1];
    float a0 = 0.f, a1 = 0.f, a2 = 0.f, a3 = 0.f;
    int e0m1 = e0 - 1;
    for (int i = s0; i < e0; i += 16) {  // masked 16-wide iters: ceil(deg/16) trips, MLP=4 throughout
        int ea = i + grp, eb = i + 4 + grp, ec = i + 8 + grp, ed = i + 12 + grp;
        int r0 = srow[min(ea, e0m1)];
        int r1 = srow[min(eb, e0m1)];
        int r2 = srow[min(ec, e0m1)];
        int r3 = srow[min(ed, e0m1)];
        uint2 u0 = gq[(unsigned int)r0 * 16 + sub];
        uint2 u1 = gq[(unsigned int)r1 * 16 + sub];
        uint2 u2 = gq[(unsigned int)r2 * 16 + sub];
        uint2 u3 = gq[(unsigned int)r3 * 16 + sub];
        if (ea < e0) { a0 += bf_lo(u0.x); a1 += bf_hi(u0.x); a2 += bf_lo(u0.y); a3 += bf_hi(u0.y); }
        if (eb < e0) { a0 += bf_lo(u1.x); a1 += bf_hi(u1.x); a2 += bf_lo(u1.y); a3 += bf_hi(u1.y); }
        if (ec < e0) { a0 += bf_lo(u2.x); a1 += bf_hi(u2.x); a2 += bf_lo(u2.y); a3 += bf_hi(u2.y); }
        if (ed < e0) { a0 += bf_lo(u3.x); a1 += bf_hi(u3.x); a2 += bf_lo(u3.y); a3 += bf_hi(u3.y); }
    }
    // merge the 4 edge-groups
    a0 += __shfl_xor(a0, 16, 64); a0 += __shfl_xor(a0, 32, 64);
    a1 += __shfl_xor(a1, 16, 64); a1 += __shfl_xor(a1, 32, 64);
    a2 += __shfl_xor(a2, 16, 64); a2 += __shfl_xor(a2, 32, 64);
    a3 += __shfl_xor(a3, 16, 64); a3 += __shfl_xor(a3, 32, 64);
    if (grp == 0) {
        uint2 su = gq[(unsigned int)node * 16 + sub];  // self-loop term
        a0 += bf_lo(su.x); a1 += bf_hi(su.x); a2 += bf_lo(su.y); a3 += bf_hi(su.y);
        float d = dis[node];
        float4 bv = *reinterpret_cast<const float4*>(&bias[4 * sub]);
        float4 o = make_float4(d * a0 + bv.x, d * a1 + bv.y, d * a2 + bv.z, d * a3 + bv.w);
        *reinterpret_cast<float4*>(&out[(size_t)node * CH + 4 * sub]) = o;  // quarter-wave 256B store
    }
}

extern "C" void kernel_launch(void* const* d_in, const int* in_sizes, int n_in,
                              void* d_out, int out_size, void* d_ws, size_t ws_size,
                              hipStream_t stream) {
    const float* x  = (const float*)d_in[0];
    const int*   ei = (const int*)d_in[1];  // [2, M] flat int32
    const float* W  = (const float*)d_in[2];
    const float* bv = (const float*)d_in[3];
    float* out = (float*)d_out;

    const int* row = ei;
    const int* col = ei + M_EDGES;

    // workspace layout (~22.4 MB; every byte read is written first -> no memset needed):
    char* ws = (char*)d_ws;
    int*          tot   = (int*)(ws + 0);                    // 1,564 B
    int*          bbase = (int*)(ws + (8 << 10));            // (NB+1)*4 B
    float*        dis   = (float*)(ws + (512 << 10));        // 400,000 B
    int*          nstart= (int*)(ws + (1024 << 10));         // 400,004 B (N+1, sentinel)
    int*          T     = (int*)(ws + (1536 << 10));         // 196*391*4 = 306,544 B
    unsigned int* g2    = (unsigned int*)(ws + (2u << 20));  // 12,800,000 B bf16 g
    unsigned int* pairs = (unsigned int*)(ws + (16u << 20)); // 6,400,000 B

    k_bhist<<<PART_BLOCKS, 256, 0, stream>>>(col, T);
    k_colsum<<<NB, 256, 0, stream>>>(T, tot);
    k_bucket_scan<<<1, 512, 0, stream>>>(tot, bbase);
    k_partition<<<PART_BLOCKS, 256, 0, stream>>>(row, col, bbase, T, pairs);
    k_fine<<<NB, 512, 0, stream>>>(bbase, pairs, nstart, dis);
    k_gemm_g<<<GBLKS, 256, 0, stream>>>(x, W, dis, g2);
    k_aggregate<<<(N_NODES + 3) / 4, 256, 0, stream>>>(nstart, (const int*)pairs, dis, g2, bv, out);
}

// Round 8
// 184.404 us; speedup vs baseline: 4.9434x; 1.1365x over previous
//
#include <hip/hip_runtime.h>

#define N_NODES 100000
#define M_EDGES 1600000
#define CH 64
#define NPB 128                              // nodes per bucket (col >> 7)
#define NB ((N_NODES + NPB - 1) / NPB)       // 782 buckets
#define PART_CHUNK 8192
#define PART_BLOCKS ((M_EDGES + PART_CHUNK - 1) / PART_CHUNK)  // 196
#define REG_E 12                             // 256 thr * 12 = 3072 bucket cap (mean 2046, +22 sigma)
#define GROWS 192                            // gemm rows per block
#define GBLKS ((N_NODES + GROWS - 1) / GROWS)  // 521

// f32 -> bf16 (RNE) pack of two channels into one uint
__device__ __forceinline__ unsigned int pack_bf16x2(float a, float b) {
    unsigned int ua = __float_as_uint(a);
    ua = (ua + 0x7fffu + ((ua >> 16) & 1u)) >> 16;
    unsigned int ub = __float_as_uint(b);
    ub = (ub + 0x7fffu + ((ub >> 16) & 1u)) >> 16;
    return ua | (ub << 16);
}
__device__ __forceinline__ float bf_lo(unsigned int u) { return __uint_as_float(u << 16); }
__device__ __forceinline__ float bf_hi(unsigned int u) { return __uint_as_float(u & 0xffff0000u); }

// ---------- bucket histogram: per-chunk 782-bin hist -> table T[chunk][bucket] ----------
__global__ __launch_bounds__(256) void k_bhist(const int* __restrict__ col, int* __restrict__ T) {
    __shared__ int h[NB];
    int tid = threadIdx.x;
    for (int i = tid; i < NB; i += 256) h[i] = 0;
    __syncthreads();
    const int4* c4 = (const int4*)col;
    int start4 = blockIdx.x * (PART_CHUNK / 4);
    int end4 = min(M_EDGES / 4, start4 + PART_CHUNK / 4);
    for (int e = start4 + tid; e < end4; e += 256) {
        int4 v = c4[e];
        atomicAdd(&h[v.x >> 7], 1);
        atomicAdd(&h[v.y >> 7], 1);
        atomicAdd(&h[v.z >> 7], 1);
        atomicAdd(&h[v.w >> 7], 1);
    }
    __syncthreads();
    for (int i = tid; i < NB; i += 256) T[blockIdx.x * NB + i] = h[i];
}

// ---------- per-bucket: exclusive scan of T column (over chunks) in-place; emit tot ----------
__global__ __launch_bounds__(256) void k_colsum(int* __restrict__ T, int* __restrict__ tot) {
    __shared__ int s[256];
    int b = blockIdx.x, t = threadIdx.x;
    int v = (t < PART_BLOCKS) ? T[t * NB + b] : 0;
    s[t] = v;
    __syncthreads();
    for (int off = 1; off < 256; off <<= 1) {
        int tv = (t >= off) ? s[t - off] : 0;
        __syncthreads();
        s[t] += tv;
        __syncthreads();
    }
    if (t < PART_BLOCKS) T[t * NB + b] = s[t] - v;  // exclusive prefix over chunks
    if (t == 255) tot[b] = s[255];
}

// ---------- exclusive scan over 782 bucket totals -> bbase (+ sentinel) ----------
__global__ __launch_bounds__(1024) void k_bucket_scan(const int* __restrict__ tot, int* __restrict__ bbase) {
    __shared__ int s[1024];
    int t = threadIdx.x;
    int v = (t < NB) ? tot[t] : 0;
    s[t] = v;
    __syncthreads();
    for (int off = 1; off < 1024; off <<= 1) {
        int tv = (t >= off) ? s[t - off] : 0;
        __syncthreads();
        s[t] += tv;
        __syncthreads();
    }
    if (t < NB) bbase[t] = s[t] - v;      // exclusive
    if (t == NB - 1) bbase[NB] = s[t];    // sentinel = M
}

// ---------- coarse partition: single pass, bases from T, int4 reads, no global atomics ----------
__global__ __launch_bounds__(256) void k_partition(const int* __restrict__ row, const int* __restrict__ col,
                                                   const int* __restrict__ bbase, const int* __restrict__ T,
                                                   unsigned int* __restrict__ pairs) {
    __shared__ int h[NB];
    int tid = threadIdx.x;
    int c = blockIdx.x;
    for (int i = tid; i < NB; i += 256) h[i] = bbase[i] + T[c * NB + i];
    __syncthreads();
    const int4* c4 = (const int4*)col;
    const int4* r4 = (const int4*)row;
    int start4 = c * (PART_CHUNK / 4);
    int end4 = min(M_EDGES / 4, start4 + PART_CHUNK / 4);
    for (int e = start4 + tid; e < end4; e += 256) {
        int4 cc = c4[e];
        int4 rr = r4[e];
        int pos;
        pos = atomicAdd(&h[cc.x >> 7], 1);
        pairs[pos] = ((unsigned int)rr.x << 7) | (unsigned int)(cc.x & 127);
        pos = atomicAdd(&h[cc.y >> 7], 1);
        pairs[pos] = ((unsigned int)rr.y << 7) | (unsigned int)(cc.y & 127);
        pos = atomicAdd(&h[cc.z >> 7], 1);
        pairs[pos] = ((unsigned int)rr.z << 7) | (unsigned int)(cc.z & 127);
        pos = atomicAdd(&h[cc.w >> 7], 1);
        pairs[pos] = ((unsigned int)rr.w << 7) | (unsigned int)(cc.w & 127);
    }
}

// ---------- in-place per-bucket counting sort; emits nstart (+sentinel) and dis ----------
__global__ __launch_bounds__(256) void k_fine(const int* __restrict__ bbase,
                                              unsigned int* __restrict__ pairs, int* __restrict__ node_start,
                                              float* __restrict__ dis) {
    __shared__ int lcnt[NPB];
    __shared__ int lcur[NPB];
    __shared__ int ss[NPB];
    int b = blockIdx.x, t = threadIdx.x;
    int s0 = bbase[b], e0 = bbase[b + 1];

    if (t < NPB) lcnt[t] = 0;
    __syncthreads();

    unsigned int reg[REG_E];  // compile-time indexed only (rule #20)
#pragma unroll
    for (int k = 0; k < REG_E; k++) {
        int e = s0 + t + k * 256;
        if (e < e0) {
            unsigned int p = pairs[e];
            reg[k] = p;
            atomicAdd(&lcnt[p & 127u], 1);
        }
    }
    __syncthreads();

    int v = 0;
    if (t < NPB) { v = lcnt[t]; ss[t] = v; }
    __syncthreads();
    for (int off = 1; off < NPB; off <<= 1) {
        int tv = (t < NPB && t >= off) ? ss[t - off] : 0;
        __syncthreads();
        if (t < NPB) ss[t] += tv;
        __syncthreads();
    }
    if (t < NPB) {
        int excl = ss[t] - v;
        lcur[t] = excl;
        int node = b * NPB + t;
        if (node < N_NODES) {
            node_start[node] = s0 + excl;
            dis[node] = 1.0f / sqrtf((float)(v + 1));  // degree incl. self-loop
        }
        if (b == NB - 1 && t == 0) node_start[N_NODES] = e0;  // sentinel
    }
    __syncthreads();

#pragma unroll
    for (int k = 0; k < REG_E; k++) {
        int e = s0 + t + k * 256;
        if (e < e0) {
            unsigned int p = reg[k];
            int pos = atomicAdd(&lcur[p & 127u], 1);
            pairs[s0 + pos] = p >> 7;  // rows grouped by target node
        }
    }
}

// ---------- g = dis[r] * (x @ W), packed bf16; wave = 16-col quad, lane = row, 3 rows/thread ----------
__global__ __launch_bounds__(256) void k_gemm_g(const float* __restrict__ x, const float* __restrict__ W,
                                                const float* __restrict__ dis, unsigned int* __restrict__ g2) {
    __shared__ float sW[64][64];
    __shared__ float sXf[GROWS * 65];  // [row][k] with +1 pad
    int t = threadIdx.x;
    int row0 = blockIdx.x * GROWS;
    int nrows = min(GROWS, N_NODES - row0);

    for (int i = t; i < 64 * 64; i += 256) sW[i >> 6][i & 63] = W[i];
    const float4* xv = (const float4*)x;
    for (int idx = t; idx < GROWS * 16; idx += 256) {
        int r = idx >> 4, c4 = idx & 15;
        float4 v = (r < nrows) ? xv[(size_t)(row0 + r) * 16 + c4] : make_float4(0.f, 0.f, 0.f, 0.f);
        sXf[r * 65 + c4 * 4 + 0] = v.x;
        sXf[r * 65 + c4 * 4 + 1] = v.y;
        sXf[r * 65 + c4 * 4 + 2] = v.z;
        sXf[r * 65 + c4 * 4 + 3] = v.w;
    }
    __syncthreads();

    int q = t >> 6;          // wave id -> col quad
    int rid = t & 63;        // lane -> row
    int c0 = q * 16;
    float acc0[16], acc1[16], acc2[16];
#pragma unroll
    for (int j = 0; j < 16; j++) { acc0[j] = 0.f; acc1[j] = 0.f; acc2[j] = 0.f; }

    for (int k = 0; k < 64; k++) {
        float xv0 = sXf[rid * 65 + k];
        float xv1 = sXf[(rid + 64) * 65 + k];
        float xv2 = sXf[(rid + 128) * 65 + k];
        const float4* wp = (const float4*)&sW[k][c0];  // same addr across wave: broadcast
        float4 w0 = wp[0], w1 = wp[1], w2 = wp[2], w3 = wp[3];
        float wv[16] = {w0.x, w0.y, w0.z, w0.w, w1.x, w1.y, w1.z, w1.w,
                        w2.x, w2.y, w2.z, w2.w, w3.x, w3.y, w3.z, w3.w};
#pragma unroll
        for (int j = 0; j < 16; j++) {
            acc0[j] += xv0 * wv[j];
            acc1[j] += xv1 * wv[j];
            acc2[j] += xv2 * wv[j];
        }
    }

#pragma unroll
    for (int jr = 0; jr < 3; jr++) {
        int r = rid + jr * 64;
        int gr = row0 + r;
        if (r < nrows) {
            float* accp = (jr == 0) ? acc0 : (jr == 1) ? acc1 : acc2;  // unrolled: compile-time
            float d = dis[gr];
            uint4 wlo, whi;
            wlo.x = pack_bf16x2(d * accp[0], d * accp[1]);
            wlo.y = pack_bf16x2(d * accp[2], d * accp[3]);
            wlo.z = pack_bf16x2(d * accp[4], d * accp[5]);
            wlo.w = pack_bf16x2(d * accp[6], d * accp[7]);
            whi.x = pack_bf16x2(d * accp[8], d * accp[9]);
            whi.y = pack_bf16x2(d * accp[10], d * accp[11]);
            whi.z = pack_bf16x2(d * accp[12], d * accp[13]);
            whi.w = pack_bf16x2(d * accp[14], d * accp[15]);
            unsigned int base = (unsigned int)gr * 32 + q * 8;
            *reinterpret_cast<uint4*>(&g2[base]) = wlo;
            *reinterpret_cast<uint4*>(&g2[base + 4]) = whi;
        }
    }
}

// ---------- aggregation: 2 nodes/wave, 8 lanes/edge (uint4 = 8 ch), 16 edges/node/iter ----------
// out[c] = dis[c] * (sum_e g[srow_e] + g[c]) + b
__global__ __launch_bounds__(256) void k_aggregate(const int* __restrict__ nstart, const int* __restrict__ srow,
                                                   const float* __restrict__ dis, const unsigned int* __restrict__ g2,
                                                   const float* __restrict__ bias, float* __restrict__ out) {
    int node = blockIdx.x * 8 + (threadIdx.x >> 5);   // 32 lanes per node
    if (node >= N_NODES) return;
    int l = threadIdx.x & 31;
    int grp = l >> 3;   // edge slot 0..3
    int sub = l & 7;    // channel octet: channels 8*sub .. 8*sub+7
    const uint4* gq = (const uint4*)g2;  // one g-row = 8 uint4
    int s0 = nstart[node];
    int e0 = nstart[node + 1];
    float a0 = 0.f, a1 = 0.f, a2 = 0.f, a3 = 0.f, a4 = 0.f, a5 = 0.f, a6 = 0.f, a7 = 0.f;
    int e0m1 = e0 - 1;
    for (int i = s0; i < e0; i += 16) {  // masked 16-wide iters, MLP=4
        int ea = i + grp, eb = i + 4 + grp, ec = i + 8 + grp, ed = i + 12 + grp;
        int r0 = srow[min(ea, e0m1)];
        int r1 = srow[min(eb, e0m1)];
        int r2 = srow[min(ec, e0m1)];
        int r3 = srow[min(ed, e0m1)];
        uint4 u0 = gq[(unsigned int)r0 * 8 + sub];
        uint4 u1 = gq[(unsigned int)r1 * 8 + sub];
        uint4 u2 = gq[(unsigned int)r2 * 8 + sub];
        uint4 u3 = gq[(unsigned int)r3 * 8 + sub];
        if (ea < e0) { a0 += bf_lo(u0.x); a1 += bf_hi(u0.x); a2 += bf_lo(u0.y); a3 += bf_hi(u0.y);
                       a4 += bf_lo(u0.z); a5 += bf_hi(u0.z); a6 += bf_lo(u0.w); a7 += bf_hi(u0.w); }
        if (eb < e0) { a0 += bf_lo(u1.x); a1 += bf_hi(u1.x); a2 += bf_lo(u1.y); a3 += bf_hi(u1.y);
                       a4 += bf_lo(u1.z); a5 += bf_hi(u1.z); a6 += bf_lo(u1.w); a7 += bf_hi(u1.w); }
        if (ec < e0) { a0 += bf_lo(u2.x); a1 += bf_hi(u2.x); a2 += bf_lo(u2.y); a3 += bf_hi(u2.y);
                       a4 += bf_lo(u2.z); a5 += bf_hi(u2.z); a6 += bf_lo(u2.w); a7 += bf_hi(u2.w); }
        if (ed < e0) { a0 += bf_lo(u3.x); a1 += bf_hi(u3.x); a2 += bf_lo(u3.y); a3 += bf_hi(u3.y);
                       a4 += bf_lo(u3.z); a5 += bf_hi(u3.z); a6 += bf_lo(u3.w); a7 += bf_hi(u3.w); }
    }
    // merge the 4 edge-slots: xor 8,16 stay within the 32-lane node half, sub preserved
    a0 += __shfl_xor(a0, 8, 64); a0 += __shfl_xor(a0, 16, 64);
    a1 += __shfl_xor(a1, 8, 64); a1 += __shfl_xor(a1, 16, 64);
    a2 += __shfl_xor(a2, 8, 64); a2 += __shfl_xor(a2, 16, 64);
    a3 += __shfl_xor(a3, 8, 64); a3 += __shfl_xor(a3, 16, 64);
    a4 += __shfl_xor(a4, 8, 64); a4 += __shfl_xor(a4, 16, 64);
    a5 += __shfl_xor(a5, 8, 64); a5 += __shfl_xor(a5, 16, 64);
    a6 += __shfl_xor(a6, 8, 64); a6 += __shfl_xor(a6, 16, 64);
    a7 += __shfl_xor(a7, 8, 64); a7 += __shfl_xor(a7, 16, 64);
    if (grp == 0) {
        uint4 su = gq[(unsigned int)node * 8 + sub];  // self-loop term
        a0 += bf_lo(su.x); a1 += bf_hi(su.x); a2 += bf_lo(su.y); a3 += bf_hi(su.y);
        a4 += bf_lo(su.z); a5 += bf_hi(su.z); a6 += bf_lo(su.w); a7 += bf_hi(su.w);
        float d = dis[node];
        const float4* b4 = (const float4*)bias;
        float4 bv0 = b4[2 * sub], bv1 = b4[2 * sub + 1];
        float4* o4 = (float4*)&out[(size_t)node * CH + 8 * sub];
        o4[0] = make_float4(d * a0 + bv0.x, d * a1 + bv0.y, d * a2 + bv0.z, d * a3 + bv0.w);
        o4[1] = make_float4(d * a4 + bv1.x, d * a5 + bv1.y, d * a6 + bv1.z, d * a7 + bv1.w);
    }
}

extern "C" void kernel_launch(void* const* d_in, const int* in_sizes, int n_in,
                              void* d_out, int out_size, void* d_ws, size_t ws_size,
                              hipStream_t stream) {
    const float* x  = (const float*)d_in[0];
    const int*   ei = (const int*)d_in[1];  // [2, M] flat int32
    const float* W  = (const float*)d_in[2];
    const float* bv = (const float*)d_in[3];
    float* out = (float*)d_out;

    const int* row = ei;
    const int* col = ei + M_EDGES;

    // workspace layout (~22.4 MB; every byte read is written first -> no memset needed):
    char* ws = (char*)d_ws;
    int*          tot   = (int*)(ws + 0);                    // 782*4 = 3,128 B
    int*          bbase = (int*)(ws + (4 << 10));            // (NB+1)*4 = 3,132 B
    float*        dis   = (float*)(ws + (512 << 10));        // 400,000 B
    int*          nstart= (int*)(ws + (1024 << 10));         // 400,004 B (N+1, sentinel)
    int*          T     = (int*)(ws + (1536 << 10));         // 196*782*4 = 613,088 B (ends ~2.1 MB)
    unsigned int* g2    = (unsigned int*)(ws + (3u << 20));  // 12,800,000 B bf16 g (3 .. 15.8 MB)
    unsigned int* pairs = (unsigned int*)(ws + (16u << 20)); // 6,400,000 B (16 .. 22.4 MB)

    k_bhist<<<PART_BLOCKS, 256, 0, stream>>>(col, T);
    k_colsum<<<NB, 256, 0, stream>>>(T, tot);
    k_bucket_scan<<<1, 1024, 0, stream>>>(tot, bbase);
    k_partition<<<PART_BLOCKS, 256, 0, stream>>>(row, col, bbase, T, pairs);
    k_fine<<<NB, 256, 0, stream>>>(bbase, pairs, nstart, dis);
    k_gemm_g<<<GBLKS, 256, 0, stream>>>(x, W, dis, g2);
    k_aggregate<<<(N_NODES + 7) / 8, 256, 0, stream>>>(nstart, (const int*)pairs, dis, g2, bv, out);
}